// Round 1
// baseline (833.734 us; speedup 1.0000x reference)
//
#include <hip/hip_runtime.h>
#include <math.h>

// Problem constants
#define BB 32
#define NREC 64
#define CC 16
#define HW 63

// ---------------- Rectangle render ----------------
// layout[b, n, u, v] (u = col value, v = row value due to reshape with H==W):
//   border = ((u==xL || u==xR) && yT < v < yB) || ((v==yT || v==yB) && xL < u < xR)
//   value  = border ? max_c probs[b,n,c] : 0
__global__ __launch_bounds__(256) void render_kernel(const float* __restrict__ x,
                                                     float* __restrict__ layout) {
    int bn = blockIdx.x;                 // b*NREC + n
    const float* xp = x + (size_t)bn * (4 + CC);
    __shared__ int cs[4];
    __shared__ float mps;
    if (threadIdx.x == 0) {
        cs[0] = (int)xp[0]; cs[1] = (int)xp[1];
        cs[2] = (int)xp[2]; cs[3] = (int)xp[3];
        float m = xp[4];
        #pragma unroll
        for (int c = 1; c < CC; ++c) m = fmaxf(m, xp[4 + c]);
        mps = m;
    }
    __syncthreads();
    int xL = cs[0], yT = cs[1], xR = cs[2], yB = cs[3];
    float m = mps;
    float* op = layout + (size_t)bn * HW * HW;
    for (int p = threadIdx.x; p < HW * HW; p += blockDim.x) {
        int u = p / HW, v = p % HW;
        bool vb = ((u == xL || u == xR) && (v > yT && v < yB)) ||
                  ((v == yT || v == yB) && (u > xL && u < xR));
        op[p] = vb ? m : 0.0f;
    }
}

// ---------------- Conv (3x3, stride 2, VALID) + bias, with optional fused
// BN+ReLU applied to the INPUT, and per-block stats partials on the OUTPUT ----
template<int CIN, int COUT, int HIN, int HOUT, int NT, bool FUSE>
__global__ __launch_bounds__(NT) void conv_bn_kernel(
        const float* __restrict__ in,    // raw previous output (or layout)
        const float* __restrict__ scl,   // per-CIN scale (if FUSE)
        const float* __restrict__ shf,   // per-CIN shift (if FUSE)
        const float* __restrict__ w,     // [COUT][CIN][3][3]
        const float* __restrict__ bias,  // [COUT]
        float* __restrict__ out,         // [B][COUT][HOUT][HOUT] raw (pre-BN)
        float* __restrict__ psum,        // [B*COUT] per-block partial sums
        float* __restrict__ psq) {
    __shared__ float wsm[CIN * 9];
    __shared__ float sscale[CIN];
    __shared__ float sshift[CIN];
    __shared__ float rs[NT];
    __shared__ float rq[NT];

    int tid = threadIdx.x;
    int b  = blockIdx.x / COUT;
    int co = blockIdx.x % COUT;

    for (int i = tid; i < CIN * 9; i += NT) wsm[i] = w[(size_t)co * CIN * 9 + i];
    if (FUSE) {
        for (int i = tid; i < CIN; i += NT) { sscale[i] = scl[i]; sshift[i] = shf[i]; }
    }
    __syncthreads();

    const float* inb = in + (size_t)b * CIN * HIN * HIN;
    float bco = bias[co];
    float lsum = 0.f, lsq = 0.f;

    for (int p = tid; p < HOUT * HOUT; p += NT) {
        int oy = p / HOUT, ox = p % HOUT;
        const float* ibase = inb + (oy * 2) * HIN + (ox * 2);
        float acc = 0.f;
        for (int ci = 0; ci < CIN; ++ci) {
            const float* ip = ibase + (size_t)ci * HIN * HIN;
            const float* wp = wsm + ci * 9;
            float s_ = FUSE ? sscale[ci] : 0.f;
            float h_ = FUSE ? sshift[ci] : 0.f;
            #pragma unroll
            for (int ky = 0; ky < 3; ++ky) {
                float a0 = ip[ky * HIN + 0];
                float a1 = ip[ky * HIN + 1];
                float a2 = ip[ky * HIN + 2];
                if (FUSE) {
                    a0 = fmaxf(fmaf(a0, s_, h_), 0.f);
                    a1 = fmaxf(fmaf(a1, s_, h_), 0.f);
                    a2 = fmaxf(fmaf(a2, s_, h_), 0.f);
                }
                acc = fmaf(a0, wp[ky * 3 + 0], acc);
                acc = fmaf(a1, wp[ky * 3 + 1], acc);
                acc = fmaf(a2, wp[ky * 3 + 2], acc);
            }
        }
        acc += bco;
        out[((size_t)b * COUT + co) * (HOUT * HOUT) + p] = acc;
        lsum += acc;
        lsq  += acc * acc;
    }

    rs[tid] = lsum; rq[tid] = lsq;
    __syncthreads();
    for (int s = NT / 2; s > 0; s >>= 1) {
        if (tid < s) { rs[tid] += rs[tid + s]; rq[tid] += rq[tid + s]; }
        __syncthreads();
    }
    if (tid == 0) { psum[blockIdx.x] = rs[0]; psq[blockIdx.x] = rq[0]; }
}

// ---------------- Fold partials -> per-channel scale/shift ----------------
__global__ void stats_kernel(const float* __restrict__ psum, const float* __restrict__ psq,
                             const float* __restrict__ g, const float* __restrict__ be,
                             float* __restrict__ scale, float* __restrict__ shift,
                             int COUT, float count) {
    int c = threadIdx.x;
    if (c >= COUT) return;
    float s = 0.f, q = 0.f;
    for (int b = 0; b < BB; ++b) { s += psum[b * COUT + c]; q += psq[b * COUT + c]; }
    float mean = s / count;
    float var  = q / count - mean * mean;
    float sc   = g[c] * rsqrtf(var + 1e-5f);
    scale[c] = sc;
    shift[c] = be[c] - mean * sc;
}

// ---------------- FC head: relu(bn3) -> fc1(+relu) -> fc2 -> sigmoid --------
__global__ __launch_bounds__(256) void fc_kernel(
        const float* __restrict__ out3,   // [B][128][7][7] raw
        const float* __restrict__ scale3, const float* __restrict__ shift3,
        const float* __restrict__ fc1w,   // [64][6272]
        const float* __restrict__ fc1b,   // [64]
        const float* __restrict__ fc2w,   // [1][64]
        const float* __restrict__ fc2b,   // [1]
        float* __restrict__ outp) {
    const int FLAT = 128 * 49;  // 6272
    int b = blockIdx.x;
    __shared__ float xin[FLAT];
    __shared__ float h[64];
    const float* ip = out3 + (size_t)b * FLAT;
    for (int i = threadIdx.x; i < FLAT; i += 256) {
        int c = i / 49;
        xin[i] = fmaxf(fmaf(ip[i], scale3[c], shift3[c]), 0.f);
    }
    __syncthreads();

    int wv = threadIdx.x >> 6, lane = threadIdx.x & 63;
    for (int jj = 0; jj < 16; ++jj) {
        int j = wv * 16 + jj;
        const float* wp = fc1w + (size_t)j * FLAT;
        float s = 0.f;
        for (int i = lane; i < FLAT; i += 64) s = fmaf(xin[i], wp[i], s);
        #pragma unroll
        for (int o = 32; o > 0; o >>= 1) s += __shfl_down(s, o, 64);
        if (lane == 0) h[j] = fmaxf(s + fc1b[j], 0.f);
    }
    __syncthreads();

    if (threadIdx.x < 64) {
        float v = h[threadIdx.x] * fc2w[threadIdx.x];
        #pragma unroll
        for (int o = 32; o > 0; o >>= 1) v += __shfl_down(v, o, 64);
        if (threadIdx.x == 0) outp[b] = 1.f / (1.f + expf(-(v + fc2b[0])));
    }
}

// ---------------- Launch ----------------
extern "C" void kernel_launch(void* const* d_in, const int* in_sizes, int n_in,
                              void* d_out, int out_size, void* d_ws, size_t ws_size,
                              hipStream_t stream) {
    const float* x       = (const float*)d_in[0];
    const float* conv1_w = (const float*)d_in[1];
    const float* conv1_b = (const float*)d_in[2];
    const float* bn1_g   = (const float*)d_in[3];
    const float* bn1_b   = (const float*)d_in[4];
    const float* conv2_w = (const float*)d_in[5];
    const float* conv2_b = (const float*)d_in[6];
    const float* bn2_g   = (const float*)d_in[7];
    const float* bn2_b   = (const float*)d_in[8];
    const float* conv3_w = (const float*)d_in[9];
    const float* conv3_b = (const float*)d_in[10];
    const float* bn3_g   = (const float*)d_in[11];
    const float* bn3_b   = (const float*)d_in[12];
    const float* fc1_w   = (const float*)d_in[13];
    const float* fc1_b   = (const float*)d_in[14];
    const float* fc2_w   = (const float*)d_in[15];
    const float* fc2_b   = (const float*)d_in[16];
    float* out = (float*)d_out;

    float* ws = (float*)d_ws;
    // Workspace layout (float offsets)
    size_t off = 0;
    float* layout = ws + off; off += (size_t)BB * NREC * HW * HW;      // 8,128,512
    float* out1   = ws + off; off += (size_t)BB * 64  * 31 * 31;       // 1,968,128
    float* out2   = ws + off; off += (size_t)BB * 128 * 15 * 15;       //   921,600
    float* out3   = ws + off; off += (size_t)BB * 128 * 7 * 7;         //   200,704
    float* psum1  = ws + off; off += BB * 64;
    float* psq1   = ws + off; off += BB * 64;
    float* psum2  = ws + off; off += BB * 128;
    float* psq2   = ws + off; off += BB * 128;
    float* psum3  = ws + off; off += BB * 128;
    float* psq3   = ws + off; off += BB * 128;
    float* scale1 = ws + off; off += 64;
    float* shift1 = ws + off; off += 64;
    float* scale2 = ws + off; off += 128;
    float* shift2 = ws + off; off += 128;
    float* scale3 = ws + off; off += 128;
    float* shift3 = ws + off; off += 128;

    // 1) render
    render_kernel<<<BB * NREC, 256, 0, stream>>>(x, layout);

    // 2) conv1 (no input BN) -> out1 raw + partials
    conv_bn_kernel<64, 64, 63, 31, 256, false><<<BB * 64, 256, 0, stream>>>(
        layout, nullptr, nullptr, conv1_w, conv1_b, out1, psum1, psq1);
    stats_kernel<<<1, 64, 0, stream>>>(psum1, psq1, bn1_g, bn1_b, scale1, shift1,
                                       64, (float)(BB * 31 * 31));

    // 3) conv2 (fused relu(bn1) on input) -> out2 raw + partials
    conv_bn_kernel<64, 128, 31, 15, 256, true><<<BB * 128, 256, 0, stream>>>(
        out1, scale1, shift1, conv2_w, conv2_b, out2, psum2, psq2);
    stats_kernel<<<1, 128, 0, stream>>>(psum2, psq2, bn2_g, bn2_b, scale2, shift2,
                                        128, (float)(BB * 15 * 15));

    // 4) conv3 (fused relu(bn2) on input) -> out3 raw + partials
    conv_bn_kernel<128, 128, 15, 7, 64, true><<<BB * 128, 64, 0, stream>>>(
        out2, scale2, shift2, conv3_w, conv3_b, out3, psum3, psq3);
    stats_kernel<<<1, 128, 0, stream>>>(psum3, psq3, bn3_g, bn3_b, scale3, shift3,
                                        128, (float)(BB * 7 * 7));

    // 5) FC head
    fc_kernel<<<BB, 256, 0, stream>>>(out3, scale3, shift3, fc1_w, fc1_b,
                                      fc2_w, fc2_b, out);
}

// Round 2
// 399.788 us; speedup vs baseline: 2.0854x; 2.0854x over previous
//
#include <hip/hip_runtime.h>
#include <math.h>

// Problem constants
#define BB 32
#define NREC 64
#define CC 16
#define HW 63

// ---------------- Rectangle render ----------------
__global__ __launch_bounds__(256) void render_kernel(const float* __restrict__ x,
                                                     float* __restrict__ layout) {
    int bn = blockIdx.x;                 // b*NREC + n
    const float* xp = x + (size_t)bn * (4 + CC);
    __shared__ int cs[4];
    __shared__ float mps;
    if (threadIdx.x == 0) {
        cs[0] = (int)xp[0]; cs[1] = (int)xp[1];
        cs[2] = (int)xp[2]; cs[3] = (int)xp[3];
        float m = xp[4];
        #pragma unroll
        for (int c = 1; c < CC; ++c) m = fmaxf(m, xp[4 + c]);
        mps = m;
    }
    __syncthreads();
    int xL = cs[0], yT = cs[1], xR = cs[2], yB = cs[3];
    float m = mps;
    float* op = layout + (size_t)bn * HW * HW;
    for (int p = threadIdx.x; p < HW * HW; p += blockDim.x) {
        int u = p / HW, v = p % HW;
        bool vb = ((u == xL || u == xR) && (v > yT && v < yB)) ||
                  ((v == yT || v == yB) && (u > xL && u < xR));
        op[p] = vb ? m : 0.0f;
    }
}

// ---------------- Conv (3x3, stride 2, VALID) + bias, optional fused input
// BN+ReLU, per-block output stats partials ----------------
template<int CIN, int COUT, int HIN, int HOUT, int NT, bool FUSE>
__global__ __launch_bounds__(NT) void conv_bn_kernel(
        const float* __restrict__ in,
        const float* __restrict__ scl,
        const float* __restrict__ shf,
        const float* __restrict__ w,     // [COUT][CIN][3][3]
        const float* __restrict__ bias,
        float* __restrict__ out,         // raw (pre-BN)
        float* __restrict__ psum,
        float* __restrict__ psq) {
    __shared__ float wsm[CIN * 9];
    __shared__ float sscale[CIN];
    __shared__ float sshift[CIN];
    __shared__ float rs[NT];
    __shared__ float rq[NT];

    int tid = threadIdx.x;
    int b  = blockIdx.x / COUT;
    int co = blockIdx.x % COUT;

    for (int i = tid; i < CIN * 9; i += NT) wsm[i] = w[(size_t)co * CIN * 9 + i];
    if (FUSE) {
        for (int i = tid; i < CIN; i += NT) { sscale[i] = scl[i]; sshift[i] = shf[i]; }
    }
    __syncthreads();

    const float* inb = in + (size_t)b * CIN * HIN * HIN;
    float bco = bias[co];
    float lsum = 0.f, lsq = 0.f;

    for (int p = tid; p < HOUT * HOUT; p += NT) {
        int oy = p / HOUT, ox = p % HOUT;
        const float* ibase = inb + (oy * 2) * HIN + (ox * 2);
        float acc = 0.f;
        for (int ci = 0; ci < CIN; ++ci) {
            const float* ip = ibase + (size_t)ci * HIN * HIN;
            const float* wp = wsm + ci * 9;
            float s_ = FUSE ? sscale[ci] : 0.f;
            float h_ = FUSE ? sshift[ci] : 0.f;
            #pragma unroll
            for (int ky = 0; ky < 3; ++ky) {
                float a0 = ip[ky * HIN + 0];
                float a1 = ip[ky * HIN + 1];
                float a2 = ip[ky * HIN + 2];
                if (FUSE) {
                    a0 = fmaxf(fmaf(a0, s_, h_), 0.f);
                    a1 = fmaxf(fmaf(a1, s_, h_), 0.f);
                    a2 = fmaxf(fmaf(a2, s_, h_), 0.f);
                }
                acc = fmaf(a0, wp[ky * 3 + 0], acc);
                acc = fmaf(a1, wp[ky * 3 + 1], acc);
                acc = fmaf(a2, wp[ky * 3 + 2], acc);
            }
        }
        acc += bco;
        out[((size_t)b * COUT + co) * (HOUT * HOUT) + p] = acc;
        lsum += acc;
        lsq  += acc * acc;
    }

    rs[tid] = lsum; rq[tid] = lsq;
    __syncthreads();
    for (int s = NT / 2; s > 0; s >>= 1) {
        if (tid < s) { rs[tid] += rs[tid + s]; rq[tid] += rq[tid + s]; }
        __syncthreads();
    }
    if (tid == 0) { psum[blockIdx.x] = rs[0]; psq[blockIdx.x] = rq[0]; }
}

// ---------------- Fold partials -> per-channel scale/shift ----------------
__global__ void stats_kernel(const float* __restrict__ psum, const float* __restrict__ psq,
                             const float* __restrict__ g, const float* __restrict__ be,
                             float* __restrict__ scale, float* __restrict__ shift,
                             int COUT, float count) {
    int c = threadIdx.x;
    if (c >= COUT) return;
    float s = 0.f, q = 0.f;
    for (int b = 0; b < BB; ++b) { s += psum[b * COUT + c]; q += psq[b * COUT + c]; }
    float mean = s / count;
    float var  = q / count - mean * mean;
    float sc   = g[c] * rsqrtf(var + 1e-5f);
    scale[c] = sc;
    shift[c] = be[c] - mean * sc;
}

// ---------------- FC1: one block per (b, j) ----------------
// h[b][j] = relu( sum_i relu(bn3(out3[b,i])) * fc1w[j,i] + fc1b[j] )
__global__ __launch_bounds__(256) void fc1_kernel(
        const float* __restrict__ out3,   // [B][128*49] raw
        const float* __restrict__ scale3, const float* __restrict__ shift3,
        const float* __restrict__ fc1w,   // [64][6272]
        const float* __restrict__ fc1b,   // [64]
        float* __restrict__ h) {          // [B][64]
    const int FLAT = 128 * 49;  // 6272
    int b = blockIdx.x >> 6;
    int j = blockIdx.x & 63;
    const float* ip = out3 + (size_t)b * FLAT;
    const float* wp = fc1w + (size_t)j * FLAT;
    float s = 0.f;
    for (int i = threadIdx.x; i < FLAT; i += 256) {
        int c = i / 49;
        float xv = fmaxf(fmaf(ip[i], scale3[c], shift3[c]), 0.f);
        s = fmaf(xv, wp[i], s);
    }
    #pragma unroll
    for (int o = 32; o > 0; o >>= 1) s += __shfl_down(s, o, 64);
    __shared__ float red[4];
    if ((threadIdx.x & 63) == 0) red[threadIdx.x >> 6] = s;
    __syncthreads();
    if (threadIdx.x == 0) {
        float t = red[0] + red[1] + red[2] + red[3];
        h[b * 64 + j] = fmaxf(t + fc1b[j], 0.f);
    }
}

// ---------------- FC2 + sigmoid: one block (64 lanes) per b ----------------
__global__ __launch_bounds__(64) void fc2_kernel(
        const float* __restrict__ h, const float* __restrict__ fc2w,
        const float* __restrict__ fc2b, float* __restrict__ outp) {
    int b = blockIdx.x;
    float v = h[b * 64 + threadIdx.x] * fc2w[threadIdx.x];
    #pragma unroll
    for (int o = 32; o > 0; o >>= 1) v += __shfl_down(v, o, 64);
    if (threadIdx.x == 0) outp[b] = 1.f / (1.f + expf(-(v + fc2b[0])));
}

// ---------------- Launch ----------------
extern "C" void kernel_launch(void* const* d_in, const int* in_sizes, int n_in,
                              void* d_out, int out_size, void* d_ws, size_t ws_size,
                              hipStream_t stream) {
    const float* x       = (const float*)d_in[0];
    const float* conv1_w = (const float*)d_in[1];
    const float* conv1_b = (const float*)d_in[2];
    const float* bn1_g   = (const float*)d_in[3];
    const float* bn1_b   = (const float*)d_in[4];
    const float* conv2_w = (const float*)d_in[5];
    const float* conv2_b = (const float*)d_in[6];
    const float* bn2_g   = (const float*)d_in[7];
    const float* bn2_b   = (const float*)d_in[8];
    const float* conv3_w = (const float*)d_in[9];
    const float* conv3_b = (const float*)d_in[10];
    const float* bn3_g   = (const float*)d_in[11];
    const float* bn3_b   = (const float*)d_in[12];
    const float* fc1_w   = (const float*)d_in[13];
    const float* fc1_b   = (const float*)d_in[14];
    const float* fc2_w   = (const float*)d_in[15];
    const float* fc2_b   = (const float*)d_in[16];
    float* out = (float*)d_out;

    float* ws = (float*)d_ws;
    size_t off = 0;
    float* layout = ws + off; off += (size_t)BB * NREC * HW * HW;
    float* out1   = ws + off; off += (size_t)BB * 64  * 31 * 31;
    float* out2   = ws + off; off += (size_t)BB * 128 * 15 * 15;
    float* out3   = ws + off; off += (size_t)BB * 128 * 7 * 7;
    float* psum1  = ws + off; off += BB * 64;
    float* psq1   = ws + off; off += BB * 64;
    float* psum2  = ws + off; off += BB * 128;
    float* psq2   = ws + off; off += BB * 128;
    float* psum3  = ws + off; off += BB * 128;
    float* psq3   = ws + off; off += BB * 128;
    float* scale1 = ws + off; off += 64;
    float* shift1 = ws + off; off += 64;
    float* scale2 = ws + off; off += 128;
    float* shift2 = ws + off; off += 128;
    float* scale3 = ws + off; off += 128;
    float* shift3 = ws + off; off += 128;
    float* hbuf   = ws + off; off += BB * 64;

    render_kernel<<<BB * NREC, 256, 0, stream>>>(x, layout);

    conv_bn_kernel<64, 64, 63, 31, 256, false><<<BB * 64, 256, 0, stream>>>(
        layout, nullptr, nullptr, conv1_w, conv1_b, out1, psum1, psq1);
    stats_kernel<<<1, 64, 0, stream>>>(psum1, psq1, bn1_g, bn1_b, scale1, shift1,
                                       64, (float)(BB * 31 * 31));

    conv_bn_kernel<64, 128, 31, 15, 256, true><<<BB * 128, 256, 0, stream>>>(
        out1, scale1, shift1, conv2_w, conv2_b, out2, psum2, psq2);
    stats_kernel<<<1, 128, 0, stream>>>(psum2, psq2, bn2_g, bn2_b, scale2, shift2,
                                        128, (float)(BB * 15 * 15));

    conv_bn_kernel<128, 128, 15, 7, 64, true><<<BB * 128, 64, 0, stream>>>(
        out2, scale2, shift2, conv3_w, conv3_b, out3, psum3, psq3);
    stats_kernel<<<1, 128, 0, stream>>>(psum3, psq3, bn3_g, bn3_b, scale3, shift3,
                                        128, (float)(BB * 7 * 7));

    fc1_kernel<<<BB * 64, 256, 0, stream>>>(out3, scale3, shift3, fc1_w, fc1_b, hbuf);
    fc2_kernel<<<BB, 64, 0, stream>>>(hbuf, fc2_w, fc2_b, out);
}